// Round 1
// baseline (63.313 us; speedup 1.0000x reference)
//
#include <hip/hip_runtime.h>
#include <math.h>

#define NQ 10
#define DIM 1024
#define HID 64
#define NTHREADS 256
#define PER (DIM / NTHREADS)   // 4 amplitudes per thread

__global__ __launch_bounds__(NTHREADS) void qsa_kernel(
    const float* __restrict__ x,
    const float* __restrict__ rx0,
    const float* __restrict__ ry0,
    const float* __restrict__ ry1,
    const int*   __restrict__ op_codes,
    float* __restrict__ out)
{
    __shared__ float sr[DIM];
    __shared__ float si[DIM];
    __shared__ float gc[3 * NQ], gs[3 * NQ];   // rx0 | ry0 | ry1 half-angle cos/sin
    __shared__ int   s_xm[HID], s_yzm[HID], s_ny[HID];
    __shared__ float wsum[4];

    const int tid  = threadIdx.x;
    const int lane = tid & 63;
    const int wave = tid >> 6;
    const int row  = blockIdx.x;           // 0 .. B*T-1

    // ---- per-block metadata (cheap, recomputed each block) ----
    if (tid < NQ)            { float t = 0.5f * rx0[tid];          gc[tid] = cosf(t); gs[tid] = sinf(t); }
    else if (tid < 2 * NQ)   { float t = 0.5f * ry0[tid - NQ];     gc[tid] = cosf(t); gs[tid] = sinf(t); }
    else if (tid < 3 * NQ)   { float t = 0.5f * ry1[tid - 2 * NQ]; gc[tid] = cosf(t); gs[tid] = sinf(t); }

    if (tid >= 64 && tid < 64 + HID) {
        int o = tid - 64;
        int xm = 0, yzm = 0, ny = 0;
        for (int q = 0; q < NQ; q++) {
            int code = op_codes[o * NQ + q];
            int bit  = 1 << (NQ - 1 - q);     // qubit q = bit 9-q (qubit 0 = MSB)
            if (code == 1)      { xm |= bit; }                      // X
            else if (code == 2) { xm |= bit; yzm |= bit; ny++; }    // Y
            else if (code == 3) { yzm |= bit; }                     // Z
        }
        s_xm[o] = xm; s_yzm[o] = yzm; s_ny[o] = ny & 3;
    }

    // ---- load row of x, L2-normalize into complex state (imag = 0) ----
    float xv[PER];
    float ssq = 0.f;
    const float* xr = x + (size_t)row * DIM;
    #pragma unroll
    for (int m = 0; m < PER; m++) {
        xv[m] = xr[tid + NTHREADS * m];
        ssq += xv[m] * xv[m];
    }
    #pragma unroll
    for (int off = 32; off; off >>= 1) ssq += __shfl_xor(ssq, off, 64);
    if (lane == 0) wsum[wave] = ssq;
    __syncthreads();
    const float inv = 1.0f / sqrtf(wsum[0] + wsum[1] + wsum[2] + wsum[3]);
    #pragma unroll
    for (int m = 0; m < PER; m++) {
        int d = tid + NTHREADS * m;
        sr[d] = xv[m] * inv;
        si[d] = 0.f;
    }
    __syncthreads();

    // ---- layer 1: fused RX(rx0[j]) then RY(ry0[j]) on qubit j ----
    for (int j = 0; j < NQ; j++) {
        const int p = NQ - 1 - j;
        const int mask = 1 << p;
        const float c1 = gc[j],      s1 = gs[j];       // RX
        const float c2 = gc[NQ + j], s2 = gs[NQ + j];  // RY
        for (int k = tid; k < DIM / 2; k += NTHREADS) {
            int i0 = ((k >> p) << (p + 1)) | (k & (mask - 1));
            int i1 = i0 | mask;
            float ar = sr[i0], ai = si[i0], br = sr[i1], bi = si[i1];
            // RX: a' = c1*a - i*s1*b ; b' = -i*s1*a + c1*b
            float tar = c1 * ar + s1 * bi;
            float tai = c1 * ai - s1 * br;
            float tbr = c1 * br + s1 * ai;
            float tbi = c1 * bi - s1 * ar;
            // RY: a'' = c2*a' - s2*b' ; b'' = s2*a' + c2*b'
            sr[i0] = c2 * tar - s2 * tbr;
            si[i0] = c2 * tai - s2 * tbi;
            sr[i1] = s2 * tar + c2 * tbr;
            si[i1] = s2 * tai + c2 * tbi;
        }
        __syncthreads();
    }

    // ---- CNOT ring as one composed gather permutation ----
    // phi_final[d] = phi_0[ g_1(g_2(...g_10(d))) ], g applied j=9 first.
    {
        float vr[PER], vi[PER];
        #pragma unroll
        for (int m = 0; m < PER; m++) {
            int d = tid + NTHREADS * m;
            int src = d;
            #pragma unroll
            for (int j = NQ - 1; j >= 0; j--) {
                int cp = NQ - 1 - j;                    // control bit pos
                int tp = NQ - 1 - ((j + 1) % NQ);       // target bit pos
                src ^= ((src >> cp) & 1) << tp;
            }
            vr[m] = sr[src]; vi[m] = si[src];
        }
        __syncthreads();
        #pragma unroll
        for (int m = 0; m < PER; m++) {
            int d = tid + NTHREADS * m;
            sr[d] = vr[m]; si[d] = vi[m];
        }
        __syncthreads();
    }

    // ---- layer 2: RY(ry1[j]) on qubit j ----
    for (int j = 0; j < NQ; j++) {
        const int p = NQ - 1 - j;
        const int mask = 1 << p;
        const float c = gc[2 * NQ + j], s = gs[2 * NQ + j];
        for (int k = tid; k < DIM / 2; k += NTHREADS) {
            int i0 = ((k >> p) << (p + 1)) | (k & (mask - 1));
            int i1 = i0 | mask;
            float ar = sr[i0], ai = si[i0], br = sr[i1], bi = si[i1];
            sr[i0] = c * ar - s * br;
            si[i0] = c * ai - s * bi;
            sr[i1] = s * ar + c * br;
            si[i1] = s * ai + c * bi;
        }
        __syncthreads();
    }

    // ---- observables: exps[o] = sum_d Re( conj(phi_d) * (-i)^nY * (-1)^pc * phi_{d^xm} )
    // (-i)^nY selects +D, +C, -D, -C for nY%4 = 0,1,2,3 where
    //   D = ar*br + ai*bi,  C = ar*bi - ai*br
    for (int oo = 0; oo < HID / 4; oo++) {
        int o = wave * (HID / 4) + oo;
        const int xm = s_xm[o], yzm = s_yzm[o], nym = s_ny[o];
        float acc = 0.f;
        #pragma unroll
        for (int i = 0; i < DIM / 64; i++) {
            int d = lane + 64 * i;
            float ar = sr[d], ai = si[d];
            int k = d ^ xm;
            float br = sr[k], bi = si[k];
            float v = (nym & 1) ? (ar * bi - ai * br) : (ar * br + ai * bi);
            int neg = ((nym >> 1) & 1) ^ (__popc(d & yzm) & 1);
            acc += neg ? -v : v;
        }
        #pragma unroll
        for (int off = 32; off; off >>= 1) acc += __shfl_xor(acc, off, 64);
        if (lane == 0) out[(size_t)row * HID + o] = acc;
    }
}

extern "C" void kernel_launch(void* const* d_in, const int* in_sizes, int n_in,
                              void* d_out, int out_size, void* d_ws, size_t ws_size,
                              hipStream_t stream) {
    const float* x   = (const float*)d_in[0];
    const float* rx0 = (const float*)d_in[1];
    const float* ry0 = (const float*)d_in[2];
    const float* ry1 = (const float*)d_in[3];
    const int*   op  = (const int*)d_in[4];
    float* out = (float*)d_out;
    const int rows = in_sizes[0] / DIM;   // B*T = 2048
    qsa_kernel<<<rows, NTHREADS, 0, stream>>>(x, rx0, ry0, ry1, op, out);
}

// Round 2
// 48.138 us; speedup vs baseline: 1.3152x; 1.3152x over previous
//
#include <hip/hip_runtime.h>
#include <math.h>

#define NQ 10
#define DIM 1024
#define HID 64
#define NT 256

__global__ __launch_bounds__(NT) void qsa_kernel(
    const float* __restrict__ x,
    const float* __restrict__ rx0,
    const float* __restrict__ ry0,
    const float* __restrict__ ry1,
    const int*   __restrict__ op_codes,
    float* __restrict__ out)
{
    __shared__ __align__(16) float2 st[DIM];   // state, element d at byte 8d
    __shared__ float4 s_l1[NQ];                // fused RY*RX coefs A,B,C,D per qubit
    __shared__ float2 s_l2[NQ];                // RY coefs c,s per qubit
    __shared__ int4   s_meta[HID];             // xm<<3, yzm, b, flags(bit0 Cmode, bit1 diag)
    __shared__ float4 s_tbl[HID * 4];          // per o: 8 (dh_byteoff, sign*mag) entries
    __shared__ float  wsum[4];

    const int tid  = threadIdx.x;
    const int lane = tid & 63;
    const int wave = tid >> 6;
    const int row  = blockIdx.x;

    // ---------------- setup (per-block, cheap) ----------------
    if (tid < NQ) {
        float a = 0.5f * rx0[tid], b = 0.5f * ry0[tid];
        float c1 = cosf(a), s1 = sinf(a), c2 = cosf(b), s2 = sinf(b);
        s_l1[tid] = make_float4(c1 * c2, s1 * s2, s2 * c1, c2 * s1); // A,B,C,D
    } else if (tid < 2 * NQ) {
        float a = 0.5f * ry1[tid - NQ];
        s_l2[tid - NQ] = make_float2(cosf(a), sinf(a));
    }
    if (tid >= 64 && tid < 64 + HID) {
        const int o = tid - 64;
        int xm = 0, yzm = 0, ny = 0;
        #pragma unroll
        for (int q = 0; q < NQ; q++) {
            int code = op_codes[o * NQ + q];
            int bit  = 1 << (NQ - 1 - q);          // qubit q = bit 9-q
            if (code == 1) xm |= bit;
            else if (code == 2) { xm |= bit; yzm |= bit; ny++; }
            else if (code == 3) yzm |= bit;
        }
        const int nym  = ny & 3;
        const int diag = (xm == 0) ? 1 : 0;
        const int b    = diag ? 10 : (__ffs(xm) - 1);
        s_meta[o] = make_int4(xm << 3, yzm, b, (nym & 1) | (diag << 1));
        const float mag = diag ? 1.0f : 2.0f;      // pair-doubling folded in
        const int gflip = (nym >> 1) & 1;          // (-i)^nY real-part sign
        #pragma unroll
        for (int ii = 0; ii < 4; ii++) {
            int dh[2]; float sh[2];
            #pragma unroll
            for (int u = 0; u < 2; u++) {
                int i = 2 * ii + u;
                int hi;
                if (diag) hi = 128 * i;
                else { int v = 64 * i; hi = ((v >> b) << (b + 1)) | (v & ((1 << b) - 1)); }
                dh[u] = hi << 3;
                int sg = (__popc(hi & yzm) & 1) ^ gflip;
                sh[u] = sg ? -mag : mag;
            }
            s_tbl[o * 4 + ii] = make_float4(__int_as_float(dh[0]), sh[0],
                                            __int_as_float(dh[1]), sh[1]);
        }
    }

    // ---------------- load + L2-normalize ----------------
    float vr[4], vi[4];
    float ssq = 0.f;
    const float* xr = x + (size_t)row * DIM;
    #pragma unroll
    for (int m = 0; m < 4; m++) {
        vr[m] = xr[tid + NT * m];
        vi[m] = 0.f;
        ssq += vr[m] * vr[m];
    }
    #pragma unroll
    for (int off = 32; off; off >>= 1) ssq += __shfl_xor(ssq, off, 64);
    if (lane == 0) wsum[wave] = ssq;
    __syncthreads();                                           // 1 (also fences setup)
    {
        float inv = 1.0f / sqrtf(wsum[0] + wsum[1] + wsum[2] + wsum[3]);
        #pragma unroll
        for (int m = 0; m < 4; m++) vr[m] *= inv;
    }

    // fused RY*RX 2x2 complex gate on a register pair (v0 = |0> comp)
    auto l1pair = [](const float4 g, float& r0, float& i0, float& r1, float& i1) {
        float n0r = g.x * r0 - g.y * i0 - g.z * r1 + g.w * i1;
        float n0i = g.x * i0 + g.y * r0 - g.z * i1 - g.w * r1;
        float n1r = g.z * r0 + g.w * i0 + g.x * r1 + g.y * i1;
        float n1i = g.z * i0 - g.w * r0 + g.x * i1 - g.y * r1;
        r0 = n0r; i0 = n0i; r1 = n1r; i1 = n1i;
    };
    auto l2pair = [](const float2 g, float& r0, float& i0, float& r1, float& i1) {
        float n0r = g.x * r0 - g.y * r1, n0i = g.x * i0 - g.y * i1;
        float n1r = g.y * r0 + g.x * r1, n1i = g.y * i0 + g.x * i1;
        r0 = n0r; i0 = n0i; r1 = n1r; i1 = n1i;
    };

    // ---------------- layer 1 (RX then RY per qubit; qubits commute) ----------------
    {   // p=9 (j=0), p=8 (j=1): in-register (d = tid + 256*m -> bits 9,8 = m)
        float4 g0 = s_l1[0];
        l1pair(g0, vr[0], vi[0], vr[2], vi[2]);
        l1pair(g0, vr[1], vi[1], vr[3], vi[3]);
        float4 g1 = s_l1[1];
        l1pair(g1, vr[0], vi[0], vr[1], vi[1]);
        l1pair(g1, vr[2], vi[2], vr[3], vi[3]);
    }
    #pragma unroll
    for (int m = 0; m < 4; m++) st[tid + NT * m] = make_float2(vr[m], vi[m]);
    __syncthreads();                                           // 2
    {   // p=7 (j=2), p=6 (j=3): 4x4 block per thread in LDS
        int base = lane | (wave << 8);
        float2 w00 = st[base], w01 = st[base | 64], w10 = st[base | 128], w11 = st[base | 192];
        float4 g2 = s_l1[2], g3 = s_l1[3];
        l1pair(g2, w00.x, w00.y, w10.x, w10.y);
        l1pair(g2, w01.x, w01.y, w11.x, w11.y);
        l1pair(g3, w00.x, w00.y, w01.x, w01.y);
        l1pair(g3, w10.x, w10.y, w11.x, w11.y);
        st[base] = w00; st[base | 64] = w01; st[base | 128] = w10; st[base | 192] = w11;
    }
    __syncthreads();                                           // 3
    #pragma unroll
    for (int m = 0; m < 4; m++) { float2 t = st[tid + NT * m]; vr[m] = t.x; vi[m] = t.y; }
    #pragma unroll
    for (int j = 4; j < NQ; j++) {                              // p=5..0: shuffle gates
        const int p = NQ - 1 - j;
        const int msk = 1 << p;
        float4 g = s_l1[j];
        float fsb = ((tid >> p) & 1) ? 1.f : -1.f;
        float Bs = fsb * g.y, Cs = fsb * g.z;
        #pragma unroll
        for (int m = 0; m < 4; m++) {
            float ur = __shfl_xor(vr[m], msk, 64);
            float ui = __shfl_xor(vi[m], msk, 64);
            float nr = g.x * vr[m] + Bs * vi[m] + Cs * ur + g.w * ui;
            float ni = g.x * vi[m] - Bs * vr[m] + Cs * ui - g.w * ur;
            vr[m] = nr; vi[m] = ni;
        }
    }

    // ---------------- CNOT ring: composed permutation gather ----------------
    #pragma unroll
    for (int m = 0; m < 4; m++) st[tid + NT * m] = make_float2(vr[m], vi[m]);
    __syncthreads();                                           // 4
    #pragma unroll
    for (int m = 0; m < 4; m++) {
        int d = tid + NT * m;
        int src = (d ^ (d >> 1)) ^ ((d & 1) * 0x300);
        float2 t = st[src];
        vr[m] = t.x; vi[m] = t.y;
    }
    __syncthreads();                                           // 5

    // ---------------- layer 2 (RY) ----------------
    {
        float2 g0 = s_l2[0];
        l2pair(g0, vr[0], vi[0], vr[2], vi[2]);
        l2pair(g0, vr[1], vi[1], vr[3], vi[3]);
        float2 g1 = s_l2[1];
        l2pair(g1, vr[0], vi[0], vr[1], vi[1]);
        l2pair(g1, vr[2], vi[2], vr[3], vi[3]);
    }
    #pragma unroll
    for (int m = 0; m < 4; m++) st[tid + NT * m] = make_float2(vr[m], vi[m]);
    __syncthreads();                                           // 6
    {
        int base = lane | (wave << 8);
        float2 w00 = st[base], w01 = st[base | 64], w10 = st[base | 128], w11 = st[base | 192];
        float2 g2 = s_l2[2], g3 = s_l2[3];
        l2pair(g2, w00.x, w00.y, w10.x, w10.y);
        l2pair(g2, w01.x, w01.y, w11.x, w11.y);
        l2pair(g3, w00.x, w00.y, w01.x, w01.y);
        l2pair(g3, w10.x, w10.y, w11.x, w11.y);
        st[base] = w00; st[base | 64] = w01; st[base | 128] = w10; st[base | 192] = w11;
    }
    __syncthreads();                                           // 7
    #pragma unroll
    for (int m = 0; m < 4; m++) { float2 t = st[tid + NT * m]; vr[m] = t.x; vi[m] = t.y; }
    #pragma unroll
    for (int j = 4; j < NQ; j++) {
        const int p = NQ - 1 - j;
        const int msk = 1 << p;
        float2 g = s_l2[j];
        float fsb = ((tid >> p) & 1) ? 1.f : -1.f;
        float ssf = fsb * g.y;
        #pragma unroll
        for (int m = 0; m < 4; m++) {
            float ur = __shfl_xor(vr[m], msk, 64);
            float ui = __shfl_xor(vi[m], msk, 64);
            vr[m] = g.x * vr[m] + ssf * ur;
            vi[m] = g.x * vi[m] + ssf * ui;
        }
    }
    #pragma unroll
    for (int m = 0; m < 4; m++) st[tid + NT * m] = make_float2(vr[m], vi[m]);
    __syncthreads();                                           // 8

    // ---------------- observables (16 per wave, half-set + doubling) ----------------
    const char* sb = (const char*)st;
    #pragma unroll 1
    for (int oo = 0; oo < 16; oo++) {
        const int o = wave * 16 + oo;
        int4 mt = s_meta[o];
        const int xm8 = mt.x, yzm = mt.y, b = mt.z;
        const int flu = __builtin_amdgcn_readfirstlane(mt.w);
        float acc = 0.f;
        int sl;
        if (flu & 2) {                      // diagonal (pure Z/I): full sum, float4 reads
            const int dl8 = lane << 4;      // element 2*lane
            sl = __popc((lane << 1) & yzm) & 1;
            const float pz = (yzm & 1) ? -1.f : 1.f;
            #pragma unroll
            for (int ii = 0; ii < 4; ii++) {
                float4 e = s_tbl[o * 4 + ii];
                {
                    const float4 v = *(const float4*)(sb + dl8 + __float_as_int(e.x));
                    float t = fmaf(pz, v.z * v.z + v.w * v.w, v.x * v.x + v.y * v.y);
                    acc = fmaf(e.y, t, acc);
                }
                {
                    const float4 v = *(const float4*)(sb + dl8 + __float_as_int(e.z));
                    float t = fmaf(pz, v.z * v.z + v.w * v.w, v.x * v.x + v.y * v.y);
                    acc = fmaf(e.w, t, acc);
                }
            }
        } else {
            const int dl  = ((lane >> b) << (b + 1)) | (lane & ((1 << b) - 1));
            sl = __popc(dl & yzm) & 1;
            const int dl8 = dl << 3;
            if (flu & 1) {                  // odd nY: C = ar*bi - ai*br
                #pragma unroll
                for (int ii = 0; ii < 4; ii++) {
                    float4 e = s_tbl[o * 4 + ii];
                    {
                        int d8 = dl8 + __float_as_int(e.x);
                        const float2 a = *(const float2*)(sb + d8);
                        const float2 c = *(const float2*)(sb + (d8 ^ xm8));
                        acc = fmaf(e.y, a.x * c.y - a.y * c.x, acc);
                    }
                    {
                        int d8 = dl8 + __float_as_int(e.z);
                        const float2 a = *(const float2*)(sb + d8);
                        const float2 c = *(const float2*)(sb + (d8 ^ xm8));
                        acc = fmaf(e.w, a.x * c.y - a.y * c.x, acc);
                    }
                }
            } else {                        // even nY: D = ar*br + ai*bi
                #pragma unroll
                for (int ii = 0; ii < 4; ii++) {
                    float4 e = s_tbl[o * 4 + ii];
                    {
                        int d8 = dl8 + __float_as_int(e.x);
                        const float2 a = *(const float2*)(sb + d8);
                        const float2 c = *(const float2*)(sb + (d8 ^ xm8));
                        acc = fmaf(e.y, a.x * c.x + a.y * c.y, acc);
                    }
                    {
                        int d8 = dl8 + __float_as_int(e.z);
                        const float2 a = *(const float2*)(sb + d8);
                        const float2 c = *(const float2*)(sb + (d8 ^ xm8));
                        acc = fmaf(e.w, a.x * c.x + a.y * c.y, acc);
                    }
                }
            }
        }
        acc = __int_as_float(__float_as_int(acc) ^ (sl << 31));
        #pragma unroll
        for (int off = 32; off; off >>= 1) acc += __shfl_xor(acc, off, 64);
        if (lane == 0) out[(size_t)row * HID + o] = acc;
    }
}

extern "C" void kernel_launch(void* const* d_in, const int* in_sizes, int n_in,
                              void* d_out, int out_size, void* d_ws, size_t ws_size,
                              hipStream_t stream) {
    const float* x   = (const float*)d_in[0];
    const float* rx0 = (const float*)d_in[1];
    const float* ry0 = (const float*)d_in[2];
    const float* ry1 = (const float*)d_in[3];
    const int*   op  = (const int*)d_in[4];
    float* o = (float*)d_out;
    const int rows = in_sizes[0] / DIM;    // B*T = 2048
    qsa_kernel<<<rows, NT, 0, stream>>>(x, rx0, ry0, ry1, op, o);
}